// Round 10
// baseline (489.118 us; speedup 1.0000x reference)
//
#include <hip/hip_runtime.h>
#include <stdint.h>
#include <stddef.h>

typedef unsigned short u16;
typedef unsigned int u32;
typedef unsigned long long u64;
typedef __attribute__((ext_vector_type(4))) int i32x4;
typedef __attribute__((ext_vector_type(4))) float f32x4;

#define NPOS 8192      // B*H*W
#define MROW 16384     // M
#define CDIM 1024      // C
#define QS 25.4f       // int8 quant scale (clip at ~5 sigma: essentially never)

__device__ __forceinline__ u32 fkey(float f){   // order-preserving float->uint
  union { float f; u32 u; } z; z.f = f;
  u32 b = z.u;
  return b ^ ((b & 0x80000000u) ? 0xffffffffu : 0x80000000u);
}
__device__ __forceinline__ float unfkey(u32 u){
  u32 b = (u & 0x80000000u) ? (u ^ 0x80000000u) : ~u;
  union { u32 u; float f; } z; z.u = b; return z.f;
}
__device__ __forceinline__ u64 umin64(u64 a, u64 b){ return a < b ? a : b; }
__device__ __forceinline__ u64 umax64(u64 a, u64 b){ return a > b ? a : b; }
__device__ __forceinline__ float wave_sum(float v){
  #pragma unroll
  for(int o = 32; o; o >>= 1) v += __shfl_xor(v, o, 64);
  return v;
}
__device__ __forceinline__ int q8(float x){     // signed i8 code, low 8 bits
  float y = fminf(fmaxf(x * QS, -127.f), 127.f);
  return __float2int_rn(y) & 0xff;
}

// async global->LDS, 16B per lane (wave-uniform LDS base + lane*16; global addr is per-lane)
__device__ __forceinline__ void gload16(const void* g, void* l){
  __builtin_amdgcn_global_load_lds((const __attribute__((address_space(1))) u32*)g,
                                   (__attribute__((address_space(3))) u32*)l, 16, 0, 0);
}

// ---- K1 (fused prep): blocks [0,4096): 4 mb rows per block, wave-per-row -> mq i8 + m_sq;
//      blocks [4096, 6144): feature transpose -> fT (N,C) fp32 + fq (N,C) i8 ----
__global__ __launch_bounds__(256) void k_prep(const float* __restrict__ mb, const float* __restrict__ feat,
                                              signed char* __restrict__ mq, signed char* __restrict__ fq,
                                              float* __restrict__ fT, float* __restrict__ m_sq,
                                              u32* __restrict__ minmax){
  __shared__ float tile[64][65];
  int bid = blockIdx.x, t = threadIdx.x;
  if(bid < 4096){
    int lane = t & 63, w = t >> 6;
    int row = bid * 4 + w;
    if(row == 0 && lane == 0){ minmax[0] = 0x7f800000u; minmax[1] = 0u; }
    const float4* src = (const float4*)(mb + (size_t)row * CDIM);
    u32* dst = (u32*)(mq + (size_t)row * CDIM);
    float s = 0.f;
    #pragma unroll
    for(int ch = 0; ch < 4; ch++){
      float4 v = src[ch * 64 + lane];
      u32 packed = (u32)q8(v.x) | ((u32)q8(v.y) << 8) | ((u32)q8(v.z) << 16) | ((u32)q8(v.w) << 24);
      dst[ch * 64 + lane] = packed;
      s += v.x*v.x + v.y*v.y + v.z*v.z + v.w*v.w;
    }
    s = wave_sum(s);
    if(lane == 0) m_sq[row] = s;
  } else {
    int e = bid - 4096;                 // 0..2047
    int b = e >> 8, c0 = ((e >> 4) & 15) * 64, hw0 = (e & 15) * 64;
    int a = t & 63, g = t >> 6;
    const float* fb = feat + ((size_t)b * CDIM + c0) * 1024 + hw0;
    #pragma unroll 4
    for(int r = 0; r < 16; r++){
      int cL = r * 4 + g;
      tile[cL][a] = fb[(size_t)cL * 1024 + a];      // coalesced over hw
    }
    __syncthreads();
    #pragma unroll 4
    for(int r = 0; r < 16; r++){
      int hwL = r * 4 + g;
      int n = b * 1024 + hw0 + hwL;
      int c = c0 + a;
      float x = tile[a][hwL];
      fT[(size_t)n * CDIM + c] = x;
      fq[(size_t)n * CDIM + c] = (signed char)(q8(x) << 24 >> 24);
    }
  }
}

__device__ __forceinline__ i32x4 mfma_i8(i32x4 a, i32x4 b, i32x4 c){
  return __builtin_amdgcn_mfma_i32_16x16x64_i8(a, b, c, 0, 0, 0);
}

// ---- K4: int8 GEMM, 128x128 tile, 4 waves (2x2), wave tile 64x64 (acc=64 regs ->
//          ~120 regs/wave), BK=64, 4 LDS buffers = 64KB -> 2 CO-RESIDENT blocks/CU
//          (desynced blocks overlap each other's barrier/drain stalls, m97/m114 pattern).
//          Depth-3 prefetch, counted vmcnt + raw s_barrier, swizzle identical to R7
//          (same 64B-row geometry, verified 0-conflict).
//          Epilogue: per-(row, 128-col-tile) TOP-2 argmin keys. ----
__global__ __launch_bounds__(256, 2) void k_gemm(const signed char* __restrict__ fq, const signed char* __restrict__ mq,
                                                 const float* __restrict__ m_sq, u64* __restrict__ cand){
  // [buf][A=0/B=1][row 0..127][64 i8 = 4 slots of 16B]; LDS slot s holds k-block s^((row>>1)&3)
  __shared__ unsigned char lds[4][2][128][64];   // 64 KB
  int bid = blockIdx.x;
  int xcd = bid & 7, idx = bid >> 3;           // XCD-chunked: XCD k owns ct in [16k,16k+16)
  int ct = xcd * 16 + (idx >> 6);              // 0..127
  int rt = idx & 63;                           // 0..63
  int t = threadIdx.x, lane = t & 63, wid = t >> 6;
  int wm = wid >> 1, wn = wid & 1;        // wave tile: rows wm*64, cols wn*64
  int fr = lane & 15, kg = lane >> 4;     // fragment row sel / k-slot sel (16 i8 each)
  int sr = t >> 2, sl = t & 3;            // staging: 4 slots per row, 64 rows per instr round

  // loop-carried global staging pointers (advance +64 per staged K-tile)
  int ssw = (sl ^ ((sr >> 1) & 3)) * 16;  // inverse swizzle on SOURCE ((row>>1)&3 same for sr, sr+64)
  const signed char* pA0 = fq + (size_t)(rt * 128 + sr)      * CDIM + ssw;
  const signed char* pA1 = fq + (size_t)(rt * 128 + sr + 64) * CDIM + ssw;
  const signed char* pB0 = mq + (size_t)(ct * 128 + sr)      * CDIM + ssw;
  const signed char* pB1 = mq + (size_t)(ct * 128 + sr + 64) * CDIM + ssw;
  unsigned char* Ld = &lds[0][0][sr][sl * 16];          // buf adds literal b*16384
  int fsw = (kg ^ ((fr >> 1) & 3)) * 16;                // thread-constant frag XOR slot
  const unsigned char* La = &lds[0][0][wm * 64 + fr][fsw];   // A: + mi*1024
  const unsigned char* Lb = &lds[0][1][wn * 64 + fr][fsw];   // B: + ni*1024

  const i32x4 zero = {0, 0, 0, 0};
  i32x4 acc[4][4];
  #pragma unroll
  for(int i = 0; i < 4; i++)
    #pragma unroll
    for(int j = 0; j < 4; j++) acc[i][j] = zero;

#define STAGE(BUF) do{ \
    gload16(pA0, Ld + (BUF) * 16384);              \
    gload16(pA1, Ld + (BUF) * 16384 + 4096);       \
    gload16(pB0, Ld + (BUF) * 16384 + 8192);       \
    gload16(pB1, Ld + (BUF) * 16384 + 12288);      \
    pA0 += 64; pA1 += 64; pB0 += 64; pB1 += 64;    \
  }while(0)

#define COMPUTE(BUF) do{ \
    i32x4 fb[4]; \
    _Pragma("unroll") for(int ni_ = 0; ni_ < 4; ni_++) \
      fb[ni_] = *(const i32x4*)(Lb + (BUF) * 16384 + ni_ * 1024); \
    _Pragma("unroll") for(int mi_ = 0; mi_ < 4; mi_++){ \
      i32x4 fa = *(const i32x4*)(La + (BUF) * 16384 + mi_ * 1024); \
      _Pragma("unroll") for(int ni_ = 0; ni_ < 4; ni_++) \
        acc[mi_][ni_] = mfma_i8(fa, fb[ni_], acc[mi_][ni_]); \
    } \
  }while(0)

#define SYNCV(N) asm volatile("s_waitcnt vmcnt(" #N ") lgkmcnt(0)\n\ts_barrier" ::: "memory")

  STAGE(0); STAGE(1); STAGE(2);           // tiles 0,1,2 -> bufs 0,1,2 (12 VMEM/thread in flight)
  for(int it = 0; it < 3; ++it){          // 4 K-tiles per iteration; buf literals
    SYNCV(8); STAGE(3); COMPUTE(0);
    SYNCV(8); STAGE(0); COMPUTE(1);
    SYNCV(8); STAGE(1); COMPUTE(2);
    SYNCV(8); STAGE(2); COMPUTE(3);
  }
  // tiles 12..15 (stage tile 15 now)
  SYNCV(8); STAGE(3); COMPUTE(0);         // tile 12
  SYNCV(8); COMPUTE(1);                   // tile 13
  SYNCV(4); COMPUTE(2);                   // tile 14
  SYNCV(0); COMPUTE(3);                   // tile 15

#undef STAGE
#undef COMPUTE
#undef SYNCV

  // ---- epilogue: per-row TOP-2 of (m_sq[col] - 2*cross) over this block's 128 cols ----
  const float SI = 2.0f / (QS * QS);
  float msq[4];
  #pragma unroll
  for(int ni = 0; ni < 4; ni++) msq[ni] = m_sq[ct * 128 + wn * 64 + ni * 16 + fr];
  __syncthreads();                          // all LDS reads done; safe to reuse as scratch
  u64* rl = (u64*)&lds[0][0][0][0];         // [wn][128 rows][2] = 4KB scratch
  #pragma unroll
  for(int mi = 0; mi < 4; mi++){
    #pragma unroll
    for(int j = 0; j < 4; j++){
      u64 k1 = ~0ull, k2 = ~0ull;
      #pragma unroll
      for(int ni = 0; ni < 4; ni++){
        float v = msq[ni] - SI * (float)acc[mi][ni][j];
        u64 key = ((u64)fkey(v) << 32) | (u32)(ct * 128 + wn * 64 + ni * 16 + fr);
        if(key < k1){ k2 = k1; k1 = key; } else if(key < k2){ k2 = key; }
      }
      #pragma unroll
      for(int m = 1; m < 16; m <<= 1){      // butterfly top-2 merge over the 16 fr-lanes
        u64 o1 = __shfl_xor(k1, m, 64), o2 = __shfl_xor(k2, m, 64);
        u64 n1 = umin64(k1, o1);
        u64 n2 = umin64(umax64(k1, o1), umin64(k2, o2));
        k1 = n1; k2 = n2;
      }
      if(fr == 0){
        int rowl = wm * 64 + mi * 16 + kg * 4 + j;
        rl[(wn * 128 + rowl) * 2 + 0] = k1;
        rl[(wn * 128 + rowl) * 2 + 1] = k2;
      }
    }
  }
  __syncthreads();
  if(t < 128){
    u64 a1 = rl[t * 2], a2 = rl[t * 2 + 1];
    u64 b1 = rl[(128 + t) * 2], b2 = rl[(128 + t) * 2 + 1];
    u64 n1 = umin64(a1, b1);
    u64 n2 = umin64(umax64(a1, b1), umin64(a2, b2));
    size_t base = ((size_t)(rt * 128 + t)) * 256 + ct * 2;
    cand[base] = n1; cand[base + 1] = n2;
  }
}

// ---- K5: wave-per-row finalize, zero barriers. Top-2/top-4 of 256 keys via u64 wave
//          butterflies (4 keys/lane); exact fp32 recheck (1 or 4 cands by margin) ----
__global__ __launch_bounds__(256) void k_finalize(const u64* __restrict__ cand,
    const float* __restrict__ fT,
    const float* __restrict__ mb, const float* __restrict__ m_sq,
    float* __restrict__ inf_arr, u32* __restrict__ minmax){
  int t = threadIdx.x, lane = t & 63, w = t >> 6;
  int n = blockIdx.x * 4 + w;
  const u64* cr = cand + (size_t)n * 256;
  u64 e0 = cr[lane * 4], e1 = cr[lane * 4 + 1], e2 = cr[lane * 4 + 2], e3 = cr[lane * 4 + 3];
  // per-lane sort network (keys unique: col embedded)
  u64 a0 = umin64(e0, e1), a1 = umax64(e0, e1);
  u64 a2 = umin64(e2, e3), a3 = umax64(e2, e3);
  u64 b0 = umin64(a0, a2), t2 = umax64(a0, a2);
  u64 t3 = umin64(a1, a3), b3 = umax64(a1, a3);
  u64 b1 = umin64(t2, t3), b2 = umax64(t2, t3);   // b0<=b1<=b2<=b3
  u64 k1 = b0, k2 = b1;
  #pragma unroll
  for(int m = 1; m < 64; m <<= 1){          // wave butterfly top-2 merge (all lanes converge)
    u64 o1 = __shfl_xor(k1, m, 64), o2 = __shfl_xor(k2, m, 64);
    u64 n1 = umin64(k1, o1);
    u64 n2 = umin64(umax64(k1, o1), umin64(k2, o2));
    k1 = n1; k2 = n2;
  }
  float v1 = unfkey((u32)(k1 >> 32)), v2 = unfkey((u32)(k2 >> 32));
  // margin: approx-dist2 gap; i8 quant err sigma ~1.46 pairwise -> 10 is ~6.8 sigma
  bool needm = (v2 - v1) <= 10.0f;
  u32 cols[4];
  cols[0] = (u32)k1;
  int nr = 1;
  if(needm){
    nr = 4;
    u64 l1 = b0, l2 = b1, l3 = b2, l4 = b3;   // per-lane sorted list; repeated extract-min
    #pragma unroll
    for(int it = 0; it < 4; it++){
      u64 mn = l1;
      #pragma unroll
      for(int m = 1; m < 64; m <<= 1){ u64 o = __shfl_xor(mn, m, 64); mn = umin64(mn, o); }
      cols[it] = (u32)mn;
      if(l1 == mn){ l1 = l2; l2 = l3; l3 = l4; l4 = ~0ull; }
    }
  }

  // f row in registers (exact fp32): c = lane*16 + j
  float fv[16];
  {
    const float4* fp = (const float4*)(fT + (size_t)n * CDIM) + lane * 4;
    #pragma unroll
    for(int q = 0; q < 4; q++){
      float4 v = fp[q];
      fv[q*4+0] = v.x; fv[q*4+1] = v.y; fv[q*4+2] = v.z; fv[q*4+3] = v.w;
    }
  }
  float fs = 0.f;
  #pragma unroll
  for(int j = 0; j < 16; j++) fs += fv[j] * fv[j];
  fs = wave_sum(fs);

  float bestd = 1e30f; int bestc = 0x7fffffff;
  for(int i = 0; i < nr; ++i){              // wave-uniform trip count
    int c = (int)cols[i];
    const float4* mrow = (const float4*)(mb + (size_t)c * CDIM) + lane * 4;
    float p = 0.f;
    #pragma unroll
    for(int q = 0; q < 4; q++){
      float4 mv = mrow[q];
      p += fv[q*4+0]*mv.x + fv[q*4+1]*mv.y + fv[q*4+2]*mv.z + fv[q*4+3]*mv.w;
    }
    p = wave_sum(p);
    float d = sqrtf(fmaxf(fs + m_sq[c] - 2.f * p, 0.f) + 1e-8f);
    if(d < bestd || (d == bestd && c < bestc)){ bestd = d; bestc = c; }
  }
  // influence vs the chosen nearest row (re-read; L2/L3-hot)
  {
    const float4* mrow = (const float4*)(mb + (size_t)bestc * CDIM) + lane * 4;
    float pa = 0.f;
    #pragma unroll
    for(int q = 0; q < 4; q++){
      float4 mv = mrow[q];
      pa += fabsf(fv[q*4+0]-mv.x) + fabsf(fv[q*4+1]-mv.y) + fabsf(fv[q*4+2]-mv.z) + fabsf(fv[q*4+3]-mv.w);
    }
    pa = wave_sum(pa);
    if(lane == 0){
      float inf = pa / (1024.0f * (bestd + 1e-8f));
      inf_arr[n] = inf;
      atomicMin(&minmax[0], __float_as_uint(inf));   // inf >= 0 -> bit order == float order
      atomicMax(&minmax[1], __float_as_uint(inf));
    }
  }
}

// ---- K7 (fused maps+noise): noised = features + noise * std; c0==0 blocks also emit maps ----
__global__ __launch_bounds__(256) void k_noise(const float* __restrict__ feat, const float* __restrict__ noise,
                                               const float* __restrict__ inf_arr, const u32* __restrict__ minmax,
                                               float* __restrict__ out){
  __shared__ float tile[64][65];
  __shared__ float ns[64];
  int b = blockIdx.z, c0 = blockIdx.y * 64, hw0 = blockIdx.x * 64;
  int t = threadIdx.x, a = t & 63, g = t >> 6;
  if(t < 64){
    int n = b * 1024 + hw0 + t;
    float imin = __uint_as_float(minmax[0]);
    float imax = __uint_as_float(minmax[1]);
    float denom = imax - imin;
    float x = inf_arr[n];
    float norm = (denom > 1e-8f) ? ((x - imin) / fmaxf(denom, 1e-8f)) : 0.0f;
    float nsv = 0.01f + norm * 0.49f;
    ns[t] = nsv;
    if(c0 == 0){
      out[8388608 + n] = norm;       // influence_map
      out[8396800 + n] = nsv;        // noise_std_map
    }
  }
  #pragma unroll 4
  for(int r = 0; r < 16; r++){
    int j = r * 4 + g;   // hw row
    tile[a][j] = noise[((size_t)(b * 1024 + hw0 + j)) * CDIM + c0 + a];   // coalesced over c
  }
  __syncthreads();
  #pragma unroll 4
  for(int r = 0; r < 16; r++){
    int i = r * 4 + g;   // c offset
    size_t idx = ((size_t)b * CDIM + c0 + i) * 1024 + hw0 + a;
    out[idx] = feat[idx] + tile[i][a] * ns[a];                            // coalesced over hw
  }
}

extern "C" void kernel_launch(void* const* d_in, const int* in_sizes, int n_in,
                              void* d_out, int out_size, void* d_ws, size_t ws_size,
                              hipStream_t stream){
  const float* features = (const float*)d_in[0];
  const float* mb       = (const float*)d_in[1];
  const float* noise    = (const float*)d_in[2];
  float* out = (float*)d_out;
  char* ws = (char*)d_ws;

  // fT (32MB exact fp32 transposed features) lives in d_out's noised region; overwritten last.
  float* fT = (float*)d_out;

  size_t off = 0;
  signed char* mq = (signed char*)(ws + off); off += (size_t)MROW * CDIM;   // 16MB
  signed char* fq = (signed char*)(ws + off); off += (size_t)NPOS * CDIM;   // 8MB
  float* m_sq    = (float*)(ws + off); off += (size_t)MROW * 4;
  float* inf_arr = (float*)(ws + off); off += (size_t)NPOS * 4;
  u32* minmax    = (u32*)(ws + off);   off += 256;
  u64* cand      = (u64*)(ws + off);   off += (size_t)NPOS * 256 * 8;       // 16MB

  k_prep<<<4096 + 2048, 256, 0, stream>>>(mb, features, mq, fq, fT, m_sq, minmax);
  k_gemm<<<dim3(8192), 256, 0, stream>>>(fq, mq, m_sq, cand);
  k_finalize<<<2048, 256, 0, stream>>>(cand, fT, mb, m_sq, inf_arr, minmax);
  k_noise<<<dim3(16, 16, 8), 256, 0, stream>>>(features, noise, inf_arr, minmax, out);
}

// Round 11
// 473.567 us; speedup vs baseline: 1.0328x; 1.0328x over previous
//
#include <hip/hip_runtime.h>
#include <stdint.h>
#include <stddef.h>

typedef unsigned short u16;
typedef unsigned int u32;
typedef unsigned long long u64;
typedef __attribute__((ext_vector_type(4))) int i32x4;
typedef __attribute__((ext_vector_type(4))) float f32x4;

#define NPOS 8192      // B*H*W
#define MROW 16384     // M
#define CDIM 1024      // C
#define QS 25.4f       // int8 quant scale (clip at ~5 sigma: essentially never)

__device__ __forceinline__ u32 fkey(float f){   // order-preserving float->uint
  union { float f; u32 u; } z; z.f = f;
  u32 b = z.u;
  return b ^ ((b & 0x80000000u) ? 0xffffffffu : 0x80000000u);
}
__device__ __forceinline__ float unfkey(u32 u){
  u32 b = (u & 0x80000000u) ? (u ^ 0x80000000u) : ~u;
  union { u32 u; float f; } z; z.u = b; return z.f;
}
__device__ __forceinline__ u64 umin64(u64 a, u64 b){ return a < b ? a : b; }
__device__ __forceinline__ u64 umax64(u64 a, u64 b){ return a > b ? a : b; }
__device__ __forceinline__ float wave_sum(float v){
  #pragma unroll
  for(int o = 32; o; o >>= 1) v += __shfl_xor(v, o, 64);
  return v;
}
__device__ __forceinline__ int q8(float x){     // signed i8 code, low 8 bits
  float y = fminf(fmaxf(x * QS, -127.f), 127.f);
  return __float2int_rn(y) & 0xff;
}

// async global->LDS, 16B per lane (wave-uniform LDS base + lane*16; global addr is per-lane)
__device__ __forceinline__ void gload16(const void* g, void* l){
  __builtin_amdgcn_global_load_lds((const __attribute__((address_space(1))) u32*)g,
                                   (__attribute__((address_space(3))) u32*)l, 16, 0, 0);
}

// ---- K1 (fused prep): blocks [0,4096): 4 mb rows per block, wave-per-row -> mq i8 + m_sq;
//      blocks [4096, 6144): feature transpose -> fT (N,C) fp32 + fq (N,C) i8, float4 both sides ----
__global__ __launch_bounds__(256) void k_prep(const float* __restrict__ mb, const float* __restrict__ feat,
                                              signed char* __restrict__ mq, signed char* __restrict__ fq,
                                              float* __restrict__ fT, float* __restrict__ m_sq,
                                              u32* __restrict__ minmax){
  __shared__ float tile[64][65];
  int bid = blockIdx.x, t = threadIdx.x;
  if(bid < 4096){
    int lane = t & 63, w = t >> 6;
    int row = bid * 4 + w;
    if(row == 0 && lane == 0){ minmax[0] = 0x7f800000u; minmax[1] = 0u; }
    const float4* src = (const float4*)(mb + (size_t)row * CDIM);
    u32* dst = (u32*)(mq + (size_t)row * CDIM);
    float s = 0.f;
    #pragma unroll
    for(int ch = 0; ch < 4; ch++){
      float4 v = src[ch * 64 + lane];
      u32 packed = (u32)q8(v.x) | ((u32)q8(v.y) << 8) | ((u32)q8(v.z) << 16) | ((u32)q8(v.w) << 24);
      dst[ch * 64 + lane] = packed;
      s += v.x*v.x + v.y*v.y + v.z*v.z + v.w*v.w;
    }
    s = wave_sum(s);
    if(lane == 0) m_sq[row] = s;
  } else {
    int e = bid - 4096;                 // 0..2047
    int b = e >> 8, c0 = ((e >> 4) & 15) * 64, hw0 = (e & 15) * 64;
    // load: feat[b][c0+cL][hw0+quad] -> tile[cL][hw] (float4 over hw, coalesced)
    #pragma unroll 4
    for(int r = 0; r < 4; r++){
      int li = r * 256 + t;             // 0..1023
      int cL = li >> 4, q = li & 15;
      float4 v = *((const float4*)(feat + ((size_t)b * CDIM + c0 + cL) * 1024 + hw0) + q);
      tile[cL][q * 4 + 0] = v.x; tile[cL][q * 4 + 1] = v.y;
      tile[cL][q * 4 + 2] = v.z; tile[cL][q * 4 + 3] = v.w;
    }
    __syncthreads();
    // store: fT[n][c] float4 over c + fq packed u32 (both coalesced)
    #pragma unroll 4
    for(int r = 0; r < 4; r++){
      int li = r * 256 + t;
      int hwL = li >> 4, q = li & 15;
      float4 v;
      v.x = tile[q * 4 + 0][hwL]; v.y = tile[q * 4 + 1][hwL];
      v.z = tile[q * 4 + 2][hwL]; v.w = tile[q * 4 + 3][hwL];
      int n = b * 1024 + hw0 + hwL;
      int c = c0 + q * 4;
      *((float4*)(fT + (size_t)n * CDIM + c)) = v;
      u32 packed = (u32)q8(v.x) | ((u32)q8(v.y) << 8) | ((u32)q8(v.z) << 16) | ((u32)q8(v.w) << 24);
      *((u32*)(fq + (size_t)n * CDIM + c)) = packed;
    }
  }
}

__device__ __forceinline__ i32x4 mfma_i8(i32x4 a, i32x4 b, i32x4 c){
  return __builtin_amdgcn_mfma_i32_16x16x64_i8(a, b, c, 0, 0, 0);
}

// ---- K4: int8 GEMM, 256x256 tile, 8 waves (2x4), per-wave 128x64, BK=64,
//          2 LDS buffers (64KB -> 2 CO-RESIDENT 8-wave blocks/CU; sibling block's MFMA
//          covers this block's drain stalls). Stage-next -> compute-cur -> vmcnt(0)+barrier.
//          Pointers/swizzle/epilogue verbatim from the R9 passing kernel. ----
__global__ __launch_bounds__(512, 2) void k_gemm(const signed char* __restrict__ fq, const signed char* __restrict__ mq,
                                                 const float* __restrict__ m_sq, u64* __restrict__ cand){
  // [buf][A=0/B=1][row 0..255][64 i8 = 4 slots of 16B]; LDS slot s holds k-block s^((row>>1)&3)
  __shared__ unsigned char lds[2][2][256][64];   // 64 KB
  int bid = blockIdx.x;
  int ct = (bid & 7) * 8 + ((bid >> 3) & 7);   // XCD-chunked: XCD k owns ct in [8k, 8k+8)
  int rt = bid >> 6;                           // 0..31
  int t = threadIdx.x, lane = t & 63, wid = t >> 6;
  int wm = wid >> 2, wn = wid & 3;        // wave tile: rows wm*128, cols wn*64
  int fr = lane & 15, kg = lane >> 4;     // fragment row sel / k-slot sel (16 i8 each)
  int sr = t >> 2, sl = t & 3;            // staging: 4 slots per row, 128 rows per instr round

  // loop-carried global staging pointers (advance +64 per staged K-tile)
  int ssw = (sl ^ ((sr >> 1) & 3)) * 16;  // inverse swizzle on SOURCE ((row>>1)&3 same for sr, sr+128)
  const signed char* pA0 = fq + (size_t)(rt * 256 + sr)       * CDIM + ssw;
  const signed char* pA1 = fq + (size_t)(rt * 256 + sr + 128) * CDIM + ssw;
  const signed char* pB0 = mq + (size_t)(ct * 256 + sr)       * CDIM + ssw;
  const signed char* pB1 = mq + (size_t)(ct * 256 + sr + 128) * CDIM + ssw;
  unsigned char* Ld = &lds[0][0][sr][sl * 16];          // buf adds literal b*32768
  int fsw = (kg ^ ((fr >> 1) & 3)) * 16;                // thread-constant frag XOR slot
  const unsigned char* La = &lds[0][0][wm * 128 + fr][fsw];   // A: + mi*1024
  const unsigned char* Lb = &lds[0][1][wn * 64  + fr][fsw];   // B: + ni*1024

  const i32x4 zero = {0, 0, 0, 0};
  i32x4 acc[8][4];
  #pragma unroll
  for(int i = 0; i < 8; i++)
    #pragma unroll
    for(int j = 0; j < 4; j++) acc[i][j] = zero;

#define STAGE(BUF) do{ \
    gload16(pA0, Ld + (BUF) * 32768);                  \
    gload16(pA1, Ld + (BUF) * 32768 + 8192);           \
    gload16(pB0, Ld + (BUF) * 32768 + 16384);          \
    gload16(pB1, Ld + (BUF) * 32768 + 16384 + 8192);   \
    pA0 += 64; pA1 += 64; pB0 += 64; pB1 += 64;        \
  }while(0)

#define COMPUTE(BUF) do{ \
    i32x4 fb[4]; \
    _Pragma("unroll") for(int ni_ = 0; ni_ < 4; ni_++) \
      fb[ni_] = *(const i32x4*)(Lb + (BUF) * 32768 + ni_ * 1024); \
    _Pragma("unroll") for(int mi_ = 0; mi_ < 8; mi_++){ \
      i32x4 fa = *(const i32x4*)(La + (BUF) * 32768 + mi_ * 1024); \
      _Pragma("unroll") for(int ni_ = 0; ni_ < 4; ni_++) \
        acc[mi_][ni_] = mfma_i8(fa, fb[ni_], acc[mi_][ni_]); \
    } \
  }while(0)

#define SYNC0() asm volatile("s_waitcnt vmcnt(0) lgkmcnt(0)\n\ts_barrier" ::: "memory")

  STAGE(0);
  SYNC0();
  for(int it = 0; it < 7; ++it){
    STAGE(1); COMPUTE(0); SYNC0();
    STAGE(0); COMPUTE(1); SYNC0();
  }
  STAGE(1); COMPUTE(0); SYNC0();   // tile 14 (stage tile 15)
  COMPUTE(1);                      // tile 15

#undef STAGE
#undef COMPUTE
#undef SYNC0

  // ---- epilogue: per-row TOP-2 of (m_sq[col] - 2*cross) over this block's 256 cols ----
  const float SI = 2.0f / (QS * QS);
  float msq[4];
  #pragma unroll
  for(int ni = 0; ni < 4; ni++) msq[ni] = m_sq[ct * 256 + wn * 64 + ni * 16 + fr];
  __syncthreads();                          // all LDS reads done; safe to reuse as scratch
  u64* rl = (u64*)&lds[0][0][0][0];         // [wn][256 rows][2] = 16KB
  #pragma unroll
  for(int mi = 0; mi < 8; mi++){
    #pragma unroll
    for(int j = 0; j < 4; j++){
      u64 k1 = ~0ull, k2 = ~0ull;
      #pragma unroll
      for(int ni = 0; ni < 4; ni++){
        float v = msq[ni] - SI * (float)acc[mi][ni][j];
        u64 key = ((u64)fkey(v) << 32) | (u32)(ct * 256 + wn * 64 + ni * 16 + fr);
        if(key < k1){ k2 = k1; k1 = key; } else if(key < k2){ k2 = key; }
      }
      #pragma unroll
      for(int m = 1; m < 16; m <<= 1){      // butterfly top-2 merge over the 16 fr-lanes
        u64 o1 = __shfl_xor(k1, m, 64), o2 = __shfl_xor(k2, m, 64);
        u64 n1 = umin64(k1, o1);
        u64 n2 = umin64(umax64(k1, o1), umin64(k2, o2));
        k1 = n1; k2 = n2;
      }
      if(fr == 0){
        int rowl = wm * 128 + mi * 16 + kg * 4 + j;
        rl[(wn * 256 + rowl) * 2 + 0] = k1;
        rl[(wn * 256 + rowl) * 2 + 1] = k2;
      }
    }
  }
  __syncthreads();
  if(t < 256){
    u64 a1 = rl[t * 2], a2 = rl[t * 2 + 1];
    #pragma unroll
    for(int w = 1; w < 4; w++){
      u64 b1 = rl[(w * 256 + t) * 2], b2 = rl[(w * 256 + t) * 2 + 1];
      u64 n1 = umin64(a1, b1);
      u64 n2 = umin64(umax64(a1, b1), umin64(a2, b2));
      a1 = n1; a2 = n2;
    }
    size_t base = ((size_t)(rt * 256 + t)) * 128 + ct * 2;
    cand[base] = a1; cand[base + 1] = a2;
  }
}

// ---- K5: wave-per-row finalize, zero barriers. Top-2/top-4 of 128 keys via u64 wave
//          butterflies; exact fp32 recheck (1 or 4 cands by margin); influence ----
__global__ __launch_bounds__(256) void k_finalize(const u64* __restrict__ cand,
    const float* __restrict__ fT,
    const float* __restrict__ mb, const float* __restrict__ m_sq,
    float* __restrict__ inf_arr, u32* __restrict__ minmax){
  int t = threadIdx.x, lane = t & 63, w = t >> 6;
  int n = blockIdx.x * 4 + w;
  const u64* cr = cand + (size_t)n * 128;
  u64 a = cr[lane * 2], b = cr[lane * 2 + 1];
  u64 k1 = umin64(a, b), k2 = umax64(a, b);
  #pragma unroll
  for(int m = 1; m < 64; m <<= 1){          // wave butterfly top-2 merge (all lanes converge)
    u64 o1 = __shfl_xor(k1, m, 64), o2 = __shfl_xor(k2, m, 64);
    u64 n1 = umin64(k1, o1);
    u64 n2 = umin64(umax64(k1, o1), umin64(k2, o2));
    k1 = n1; k2 = n2;
  }
  float v1 = unfkey((u32)(k1 >> 32)), v2 = unfkey((u32)(k2 >> 32));
  // margin: approx-dist2 gap; i8 quant err sigma ~1.46 pairwise -> 10 is ~6.8 sigma
  bool needm = (v2 - v1) <= 10.0f;
  u32 cols[4];
  cols[0] = (u32)k1;
  int nr = 1;
  if(needm){
    nr = 4;
    u64 l1 = umin64(a, b), l2 = umax64(a, b);  // per-lane sorted pair; repeated extract-min
    #pragma unroll
    for(int it = 0; it < 4; it++){
      u64 mn = l1;
      #pragma unroll
      for(int m = 1; m < 64; m <<= 1){ u64 o = __shfl_xor(mn, m, 64); mn = umin64(mn, o); }
      cols[it] = (u32)mn;
      if(l1 == mn){ l1 = l2; l2 = ~0ull; }
    }
  }

  // f row in registers (exact fp32): c = lane*16 + j
  float fv[16];
  {
    const float4* fp = (const float4*)(fT + (size_t)n * CDIM) + lane * 4;
    #pragma unroll
    for(int q = 0; q < 4; q++){
      float4 v = fp[q];
      fv[q*4+0] = v.x; fv[q*4+1] = v.y; fv[q*4+2] = v.z; fv[q*4+3] = v.w;
    }
  }
  float fs = 0.f;
  #pragma unroll
  for(int j = 0; j < 16; j++) fs += fv[j] * fv[j];
  fs = wave_sum(fs);

  float bestd = 1e30f; int bestc = 0x7fffffff;
  for(int i = 0; i < nr; ++i){              // wave-uniform trip count
    int c = (int)cols[i];
    const float4* mrow = (const float4*)(mb + (size_t)c * CDIM) + lane * 4;
    float p = 0.f;
    #pragma unroll
    for(int q = 0; q < 4; q++){
      float4 mv = mrow[q];
      p += fv[q*4+0]*mv.x + fv[q*4+1]*mv.y + fv[q*4+2]*mv.z + fv[q*4+3]*mv.w;
    }
    p = wave_sum(p);
    float d = sqrtf(fmaxf(fs + m_sq[c] - 2.f * p, 0.f) + 1e-8f);
    if(d < bestd || (d == bestd && c < bestc)){ bestd = d; bestc = c; }
  }
  // influence vs the chosen nearest row (re-read; L2/L3-hot)
  {
    const float4* mrow = (const float4*)(mb + (size_t)bestc * CDIM) + lane * 4;
    float pa = 0.f;
    #pragma unroll
    for(int q = 0; q < 4; q++){
      float4 mv = mrow[q];
      pa += fabsf(fv[q*4+0]-mv.x) + fabsf(fv[q*4+1]-mv.y) + fabsf(fv[q*4+2]-mv.z) + fabsf(fv[q*4+3]-mv.w);
    }
    pa = wave_sum(pa);
    if(lane == 0){
      float inf = pa / (1024.0f * (bestd + 1e-8f));
      inf_arr[n] = inf;
      atomicMin(&minmax[0], __float_as_uint(inf));   // inf >= 0 -> bit order == float order
      atomicMax(&minmax[1], __float_as_uint(inf));
    }
  }
}

// ---- K7 (fused maps+noise): noised = features + noise * std, float4 both sides;
//      c0==0 blocks also emit the influence/noise_std maps ----
__global__ __launch_bounds__(256) void k_noise(const float* __restrict__ feat, const float* __restrict__ noise,
                                               const float* __restrict__ inf_arr, const u32* __restrict__ minmax,
                                               float* __restrict__ out){
  __shared__ float tile[64][65];
  __shared__ float ns[64];
  int b = blockIdx.z, c0 = blockIdx.y * 64, hw0 = blockIdx.x * 64;
  int t = threadIdx.x;
  if(t < 64){
    int n = b * 1024 + hw0 + t;
    float imin = __uint_as_float(minmax[0]);
    float imax = __uint_as_float(minmax[1]);
    float denom = imax - imin;
    float x = inf_arr[n];
    float norm = (denom > 1e-8f) ? ((x - imin) / fmaxf(denom, 1e-8f)) : 0.0f;
    float nsv = 0.01f + norm * 0.49f;
    ns[t] = nsv;
    if(c0 == 0){
      out[8388608 + n] = norm;       // influence_map
      out[8396800 + n] = nsv;        // noise_std_map
    }
  }
  // load: noise[n=hw][c] float4 over c -> tile[c][hw]
  #pragma unroll 4
  for(int r = 0; r < 4; r++){
    int li = r * 256 + t;              // 0..1023
    int j = li >> 4, q = li & 15;      // hw row, c-quad
    float4 v = *((const float4*)(noise + ((size_t)(b * 1024 + hw0 + j)) * CDIM + c0) + q);
    tile[q * 4 + 0][j] = v.x; tile[q * 4 + 1][j] = v.y;
    tile[q * 4 + 2][j] = v.z; tile[q * 4 + 3][j] = v.w;
  }
  __syncthreads();
  // store: out[c][hw] = feat + noise^T * ns, float4 over hw
  #pragma unroll 4
  for(int r = 0; r < 4; r++){
    int li = r * 256 + t;
    int i = li >> 4, h4 = li & 15;     // c offset, hw-quad
    size_t idx = ((size_t)b * CDIM + c0 + i) * 1024 + hw0 + h4 * 4;
    float4 f = *(const float4*)(feat + idx);
    float4 o;
    o.x = f.x + tile[i][h4 * 4 + 0] * ns[h4 * 4 + 0];
    o.y = f.y + tile[i][h4 * 4 + 1] * ns[h4 * 4 + 1];
    o.z = f.z + tile[i][h4 * 4 + 2] * ns[h4 * 4 + 2];
    o.w = f.w + tile[i][h4 * 4 + 3] * ns[h4 * 4 + 3];
    *(float4*)(out + idx) = o;
  }
}

extern "C" void kernel_launch(void* const* d_in, const int* in_sizes, int n_in,
                              void* d_out, int out_size, void* d_ws, size_t ws_size,
                              hipStream_t stream){
  const float* features = (const float*)d_in[0];
  const float* mb       = (const float*)d_in[1];
  const float* noise    = (const float*)d_in[2];
  float* out = (float*)d_out;
  char* ws = (char*)d_ws;

  // fT (32MB exact fp32 transposed features) lives in d_out's noised region; overwritten last.
  float* fT = (float*)d_out;

  size_t off = 0;
  signed char* mq = (signed char*)(ws + off); off += (size_t)MROW * CDIM;   // 16MB
  signed char* fq = (signed char*)(ws + off); off += (size_t)NPOS * CDIM;   // 8MB
  float* m_sq    = (float*)(ws + off); off += (size_t)MROW * 4;
  float* inf_arr = (float*)(ws + off); off += (size_t)NPOS * 4;
  u32* minmax    = (u32*)(ws + off);   off += 256;
  u64* cand      = (u64*)(ws + off);   off += (size_t)NPOS * 128 * 8;       // 8MB

  k_prep<<<4096 + 2048, 256, 0, stream>>>(mb, features, mq, fq, fT, m_sq, minmax);
  k_gemm<<<dim3(2048), 512, 0, stream>>>(fq, mq, m_sq, cand);
  k_finalize<<<2048, 256, 0, stream>>>(cand, fT, mb, m_sq, inf_arr, minmax);
  k_noise<<<dim3(16, 16, 8), 256, 0, stream>>>(features, noise, inf_arr, minmax, out);
}

// Round 13
// 461.992 us; speedup vs baseline: 1.0587x; 1.0251x over previous
//
#include <hip/hip_runtime.h>
#include <stdint.h>
#include <stddef.h>

typedef unsigned short u16;
typedef unsigned int u32;
typedef unsigned long long u64;
typedef __attribute__((ext_vector_type(4))) int i32x4;
typedef __attribute__((ext_vector_type(4))) float f32x4;

#define NPOS 8192      // B*H*W
#define MROW 16384     // M
#define CDIM 1024      // C
#define QS 25.4f       // int8 quant scale (clip at ~5 sigma: essentially never)

__device__ __forceinline__ u32 fkey(float f){   // order-preserving float->uint
  union { float f; u32 u; } z; z.f = f;
  u32 b = z.u;
  return b ^ ((b & 0x80000000u) ? 0xffffffffu : 0x80000000u);
}
__device__ __forceinline__ float unfkey(u32 u){
  u32 b = (u & 0x80000000u) ? (u ^ 0x80000000u) : ~u;
  union { u32 u; float f; } z; z.u = b; return z.f;
}
__device__ __forceinline__ u64 umin64(u64 a, u64 b){ return a < b ? a : b; }
__device__ __forceinline__ u64 umax64(u64 a, u64 b){ return a > b ? a : b; }
__device__ __forceinline__ float wave_sum(float v){
  #pragma unroll
  for(int o = 32; o; o >>= 1) v += __shfl_xor(v, o, 64);
  return v;
}
__device__ __forceinline__ int q8(float x){     // signed i8 code, low 8 bits
  float y = fminf(fmaxf(x * QS, -127.f), 127.f);
  return __float2int_rn(y) & 0xff;
}

// async global->LDS, 16B per lane (wave-uniform LDS base + lane*16; global addr is per-lane)
__device__ __forceinline__ void gload16(const void* g, void* l){
  __builtin_amdgcn_global_load_lds((const __attribute__((address_space(1))) u32*)g,
                                   (__attribute__((address_space(3))) u32*)l, 16, 0, 0);
}

// ---- K1 (fused prep): blocks [0,4096): 4 mb rows per block, wave-per-row -> mq i8 + m_sq;
//      blocks [4096, 6144): feature transpose -> fT (N,C) fp32 + fq (N,C) i8, float4 both sides ----
__global__ __launch_bounds__(256) void k_prep(const float* __restrict__ mb, const float* __restrict__ feat,
                                              signed char* __restrict__ mq, signed char* __restrict__ fq,
                                              float* __restrict__ fT, float* __restrict__ m_sq,
                                              u32* __restrict__ minmax){
  __shared__ float tile[64][65];
  int bid = blockIdx.x, t = threadIdx.x;
  if(bid < 4096){
    int lane = t & 63, w = t >> 6;
    int row = bid * 4 + w;
    if(row == 0 && lane == 0){ minmax[0] = 0x7f800000u; minmax[1] = 0u; }
    const float4* src = (const float4*)(mb + (size_t)row * CDIM);
    u32* dst = (u32*)(mq + (size_t)row * CDIM);
    float s = 0.f;
    #pragma unroll
    for(int ch = 0; ch < 4; ch++){
      float4 v = src[ch * 64 + lane];
      u32 packed = (u32)q8(v.x) | ((u32)q8(v.y) << 8) | ((u32)q8(v.z) << 16) | ((u32)q8(v.w) << 24);
      dst[ch * 64 + lane] = packed;
      s += v.x*v.x + v.y*v.y + v.z*v.z + v.w*v.w;
    }
    s = wave_sum(s);
    if(lane == 0) m_sq[row] = s;
  } else {
    int e = bid - 4096;                 // 0..2047
    int b = e >> 8, c0 = ((e >> 4) & 15) * 64, hw0 = (e & 15) * 64;
    // load: feat[b][c0+cL][hw0+quad] -> tile[cL][hw] (float4 over hw, coalesced)
    #pragma unroll 4
    for(int r = 0; r < 4; r++){
      int li = r * 256 + t;             // 0..1023
      int cL = li >> 4, q = li & 15;
      float4 v = *((const float4*)(feat + ((size_t)b * CDIM + c0 + cL) * 1024 + hw0) + q);
      tile[cL][q * 4 + 0] = v.x; tile[cL][q * 4 + 1] = v.y;
      tile[cL][q * 4 + 2] = v.z; tile[cL][q * 4 + 3] = v.w;
    }
    __syncthreads();
    // store: fT[n][c] float4 over c + fq packed u32 (both coalesced)
    #pragma unroll 4
    for(int r = 0; r < 4; r++){
      int li = r * 256 + t;
      int hwL = li >> 4, q = li & 15;
      float4 v;
      v.x = tile[q * 4 + 0][hwL]; v.y = tile[q * 4 + 1][hwL];
      v.z = tile[q * 4 + 2][hwL]; v.w = tile[q * 4 + 3][hwL];
      int n = b * 1024 + hw0 + hwL;
      int c = c0 + q * 4;
      *((float4*)(fT + (size_t)n * CDIM + c)) = v;
      u32 packed = (u32)q8(v.x) | ((u32)q8(v.y) << 8) | ((u32)q8(v.z) << 16) | ((u32)q8(v.w) << 24);
      *((u32*)(fq + (size_t)n * CDIM + c)) = packed;
    }
  }
}

__device__ __forceinline__ i32x4 mfma16_i8(i32x4 a, i32x4 b, i32x4 c){
  return __builtin_amdgcn_mfma_i32_16x16x64_i8(a, b, c, 0, 0, 0);
}

// ---- K4: int8 GEMM, 256x256 tile, 8 waves (2x4), per-wave 128x64, BK=128 (i8),
//          2 LDS buffers (128KB), HALVED SYNC COUNT: 8 drains instead of 16 — the
//          ~2000cyc/drain fixed cost amortizes over 2x compute (occupancy already
//          reg-pinned at 1 block/CU, so the bigger LDS costs nothing).
//          128B rows = 8 slots of 16B; slot s holds k-block s^(row&7); frag read slot
//          (kc*4+kg)^(fr&7) -> 2 lanes/bank-group, conflict-free. ----
__global__ __launch_bounds__(512, 2) void k_gemm(const signed char* __restrict__ fq, const signed char* __restrict__ mq,
                                                 const float* __restrict__ m_sq, u64* __restrict__ cand){
  __shared__ unsigned char lds[2][2][256][128];   // 128 KB
  int bid = blockIdx.x;
  int ct = (bid & 7) * 8 + ((bid >> 3) & 7);   // XCD-chunked: XCD k owns ct in [8k, 8k+8)
  int rt = bid >> 6;                           // 0..31
  int t = threadIdx.x, lane = t & 63, wid = t >> 6;
  int wm = wid >> 2, wn = wid & 3;        // wave tile: rows wm*128, cols wn*64
  int fr = lane & 15, kg = lane >> 4;     // fragment row sel / k-slot sel (16 i8 each)
  int sr = t >> 3, sl = t & 7;            // staging: 8 slots per 128B row, 64 rows per round

  // loop-carried global staging pointers (advance +128 per staged K-tile)
  int ssw = (sl ^ (sr & 7)) * 16;         // inverse swizzle on SOURCE ((sr+64k)&7 == sr&7)
  const signed char* pA = fq + (size_t)(rt * 256 + sr) * CDIM + ssw;
  const signed char* pB = mq + (size_t)(ct * 256 + sr) * CDIM + ssw;
  unsigned char* Ld = &lds[0][0][sr][sl * 16];          // buf adds literal b*65536; B adds 32768
  // thread-constant fragment slot offsets for the two k-chunks (kc=0,1) of BK=128
  int fsw0 = ((0 + kg) ^ (fr & 7)) * 16;
  int fsw1 = ((4 + kg) ^ (fr & 7)) * 16;
  const unsigned char* La = &lds[0][0][wm * 128 + fr][0];   // A: + mi*2048 + fsw
  const unsigned char* Lb = &lds[0][1][wn * 64  + fr][0];   // B: + ni*2048 + fsw

  const i32x4 zero = {0, 0, 0, 0};
  i32x4 acc[8][4];
  #pragma unroll
  for(int i = 0; i < 8; i++)
    #pragma unroll
    for(int j = 0; j < 4; j++) acc[i][j] = zero;

#define STAGE(BUF) do{ \
    _Pragma("unroll") for(int r_ = 0; r_ < 4; r_++) \
      gload16(pA + (size_t)(r_ * 64) * CDIM, Ld + (BUF) * 65536 + r_ * 8192); \
    _Pragma("unroll") for(int r_ = 0; r_ < 4; r_++) \
      gload16(pB + (size_t)(r_ * 64) * CDIM, Ld + (BUF) * 65536 + 32768 + r_ * 8192); \
    pA += 128; pB += 128; \
  }while(0)

#define HALF(BUF, FS) do{ \
    i32x4 fb[4]; \
    _Pragma("unroll") for(int ni_ = 0; ni_ < 4; ni_++) \
      fb[ni_] = *(const i32x4*)(Lb + (BUF) * 65536 + ni_ * 2048 + (FS)); \
    _Pragma("unroll") for(int mi_ = 0; mi_ < 8; mi_++){ \
      i32x4 fa = *(const i32x4*)(La + (BUF) * 65536 + mi_ * 2048 + (FS)); \
      _Pragma("unroll") for(int ni_ = 0; ni_ < 4; ni_++) \
        acc[mi_][ni_] = mfma16_i8(fa, fb[ni_], acc[mi_][ni_]); \
    } \
  }while(0)

#define COMPUTE(BUF) do{ HALF(BUF, fsw0); HALF(BUF, fsw1); }while(0)
#define SYNC0() asm volatile("s_waitcnt vmcnt(0) lgkmcnt(0)\n\ts_barrier" ::: "memory")

  STAGE(0);
  SYNC0();
  for(int it = 0; it < 3; ++it){
    STAGE(1); COMPUTE(0); SYNC0();
    STAGE(0); COMPUTE(1); SYNC0();
  }
  STAGE(1); COMPUTE(0); SYNC0();   // K-tile 6 (stage tile 7)
  COMPUTE(1);                      // K-tile 7

#undef STAGE
#undef HALF
#undef COMPUTE
#undef SYNC0

  // ---- epilogue: per-row TOP-2 of (m_sq[col] - 2*cross) over this block's 256 cols ----
  const float SI = 2.0f / (QS * QS);
  float msq[4];
  #pragma unroll
  for(int ni = 0; ni < 4; ni++) msq[ni] = m_sq[ct * 256 + wn * 64 + ni * 16 + fr];
  __syncthreads();                          // all LDS reads done; safe to reuse as scratch
  u64* rl = (u64*)&lds[0][0][0][0];         // [wn][256 rows][2] = 16KB
  #pragma unroll
  for(int mi = 0; mi < 8; mi++){
    #pragma unroll
    for(int j = 0; j < 4; j++){
      u64 k1 = ~0ull, k2 = ~0ull;
      #pragma unroll
      for(int ni = 0; ni < 4; ni++){
        float v = msq[ni] - SI * (float)acc[mi][ni][j];
        u64 key = ((u64)fkey(v) << 32) | (u32)(ct * 256 + wn * 64 + ni * 16 + fr);
        if(key < k1){ k2 = k1; k1 = key; } else if(key < k2){ k2 = key; }
      }
      #pragma unroll
      for(int m = 1; m < 16; m <<= 1){      // butterfly top-2 merge over the 16 fr-lanes
        u64 o1 = __shfl_xor(k1, m, 64), o2 = __shfl_xor(k2, m, 64);
        u64 n1 = umin64(k1, o1);
        u64 n2 = umin64(umax64(k1, o1), umin64(k2, o2));
        k1 = n1; k2 = n2;
      }
      if(fr == 0){
        int rowl = wm * 128 + mi * 16 + kg * 4 + j;
        rl[(wn * 256 + rowl) * 2 + 0] = k1;
        rl[(wn * 256 + rowl) * 2 + 1] = k2;
      }
    }
  }
  __syncthreads();
  if(t < 256){
    u64 a1 = rl[t * 2], a2 = rl[t * 2 + 1];
    #pragma unroll
    for(int w = 1; w < 4; w++){
      u64 b1 = rl[(w * 256 + t) * 2], b2 = rl[(w * 256 + t) * 2 + 1];
      u64 n1 = umin64(a1, b1);
      u64 n2 = umin64(umax64(a1, b1), umin64(a2, b2));
      a1 = n1; a2 = n2;
    }
    size_t base = ((size_t)(rt * 256 + t)) * 128 + ct * 2;
    cand[base] = a1; cand[base + 1] = a2;
  }
}

// ---- K5: wave-per-row finalize, zero barriers. Top-2/top-4 of 128 keys via u64 wave
//          butterflies; exact fp32 recheck (1 or 4 cands by margin); influence ----
__global__ __launch_bounds__(256) void k_finalize(const u64* __restrict__ cand,
    const float* __restrict__ fT,
    const float* __restrict__ mb, const float* __restrict__ m_sq,
    float* __restrict__ inf_arr, u32* __restrict__ minmax){
  int t = threadIdx.x, lane = t & 63, w = t >> 6;
  int n = blockIdx.x * 4 + w;
  const u64* cr = cand + (size_t)n * 128;
  u64 a = cr[lane * 2], b = cr[lane * 2 + 1];
  u64 k1 = umin64(a, b), k2 = umax64(a, b);
  #pragma unroll
  for(int m = 1; m < 64; m <<= 1){          // wave butterfly top-2 merge (all lanes converge)
    u64 o1 = __shfl_xor(k1, m, 64), o2 = __shfl_xor(k2, m, 64);
    u64 n1 = umin64(k1, o1);
    u64 n2 = umin64(umax64(k1, o1), umin64(k2, o2));
    k1 = n1; k2 = n2;
  }
  float v1 = unfkey((u32)(k1 >> 32)), v2 = unfkey((u32)(k2 >> 32));
  // margin: approx-dist2 gap; i8 quant err sigma ~1.46 pairwise -> 10 is ~6.8 sigma
  bool needm = (v2 - v1) <= 10.0f;
  u32 cols[4];
  cols[0] = (u32)k1;
  int nr = 1;
  if(needm){
    nr = 4;
    u64 l1 = umin64(a, b), l2 = umax64(a, b);  // per-lane sorted pair; repeated extract-min
    #pragma unroll
    for(int it = 0; it < 4; it++){
      u64 mn = l1;
      #pragma unroll
      for(int m = 1; m < 64; m <<= 1){ u64 o = __shfl_xor(mn, m, 64); mn = umin64(mn, o); }
      cols[it] = (u32)mn;
      if(l1 == mn){ l1 = l2; l2 = ~0ull; }
    }
  }

  // f row in registers (exact fp32): c = lane*16 + j
  float fv[16];
  {
    const float4* fp = (const float4*)(fT + (size_t)n * CDIM) + lane * 4;
    #pragma unroll
    for(int q = 0; q < 4; q++){
      float4 v = fp[q];
      fv[q*4+0] = v.x; fv[q*4+1] = v.y; fv[q*4+2] = v.z; fv[q*4+3] = v.w;
    }
  }
  float fs = 0.f;
  #pragma unroll
  for(int j = 0; j < 16; j++) fs += fv[j] * fv[j];
  fs = wave_sum(fs);

  float bestd = 1e30f; int bestc = 0x7fffffff;
  for(int i = 0; i < nr; ++i){              // wave-uniform trip count
    int c = (int)cols[i];
    const float4* mrow = (const float4*)(mb + (size_t)c * CDIM) + lane * 4;
    float p = 0.f;
    #pragma unroll
    for(int q = 0; q < 4; q++){
      float4 mv = mrow[q];
      p += fv[q*4+0]*mv.x + fv[q*4+1]*mv.y + fv[q*4+2]*mv.z + fv[q*4+3]*mv.w;
    }
    p = wave_sum(p);
    float d = sqrtf(fmaxf(fs + m_sq[c] - 2.f * p, 0.f) + 1e-8f);
    if(d < bestd || (d == bestd && c < bestc)){ bestd = d; bestc = c; }
  }
  // influence vs the chosen nearest row (re-read; L2/L3-hot)
  {
    const float4* mrow = (const float4*)(mb + (size_t)bestc * CDIM) + lane * 4;
    float pa = 0.f;
    #pragma unroll
    for(int q = 0; q < 4; q++){
      float4 mv = mrow[q];
      pa += fabsf(fv[q*4+0]-mv.x) + fabsf(fv[q*4+1]-mv.y) + fabsf(fv[q*4+2]-mv.z) + fabsf(fv[q*4+3]-mv.w);
    }
    pa = wave_sum(pa);
    if(lane == 0){
      float inf = pa / (1024.0f * (bestd + 1e-8f));
      inf_arr[n] = inf;
      atomicMin(&minmax[0], __float_as_uint(inf));   // inf >= 0 -> bit order == float order
      atomicMax(&minmax[1], __float_as_uint(inf));
    }
  }
}

// ---- K7 (fused maps+noise): noised = features + noise * std, float4 both sides;
//      c0==0 blocks also emit the influence/noise_std maps ----
__global__ __launch_bounds__(256) void k_noise(const float* __restrict__ feat, const float* __restrict__ noise,
                                               const float* __restrict__ inf_arr, const u32* __restrict__ minmax,
                                               float* __restrict__ out){
  __shared__ float tile[64][65];
  __shared__ float ns[64];
  int b = blockIdx.z, c0 = blockIdx.y * 64, hw0 = blockIdx.x * 64;
  int t = threadIdx.x;
  if(t < 64){
    int n = b * 1024 + hw0 + t;
    float imin = __uint_as_float(minmax[0]);
    float imax = __uint_as_float(minmax[1]);
    float denom = imax - imin;
    float x = inf_arr[n];
    float norm = (denom > 1e-8f) ? ((x - imin) / fmaxf(denom, 1e-8f)) : 0.0f;
    float nsv = 0.01f + norm * 0.49f;
    ns[t] = nsv;
    if(c0 == 0){
      out[8388608 + n] = norm;       // influence_map
      out[8396800 + n] = nsv;        // noise_std_map
    }
  }
  // load: noise[n=hw][c] float4 over c -> tile[c][hw]
  #pragma unroll 4
  for(int r = 0; r < 4; r++){
    int li = r * 256 + t;              // 0..1023
    int j = li >> 4, q = li & 15;      // hw row, c-quad
    float4 v = *((const float4*)(noise + ((size_t)(b * 1024 + hw0 + j)) * CDIM + c0) + q);
    tile[q * 4 + 0][j] = v.x; tile[q * 4 + 1][j] = v.y;
    tile[q * 4 + 2][j] = v.z; tile[q * 4 + 3][j] = v.w;
  }
  __syncthreads();
  // store: out[c][hw] = feat + noise^T * ns, float4 over hw
  #pragma unroll 4
  for(int r = 0; r < 4; r++){
    int li = r * 256 + t;
    int i = li >> 4, h4 = li & 15;     // c offset, hw-quad
    size_t idx = ((size_t)b * CDIM + c0 + i) * 1024 + hw0 + h4 * 4;
    float4 f = *(const float4*)(feat + idx);
    float4 o;
    o.x = f.x + tile[i][h4 * 4 + 0] * ns[h4 * 4 + 0];
    o.y = f.y + tile[i][h4 * 4 + 1] * ns[h4 * 4 + 1];
    o.z = f.z + tile[i][h4 * 4 + 2] * ns[h4 * 4 + 2];
    o.w = f.w + tile[i][h4 * 4 + 3] * ns[h4 * 4 + 3];
    *(float4*)(out + idx) = o;
  }
}

extern "C" void kernel_launch(void* const* d_in, const int* in_sizes, int n_in,
                              void* d_out, int out_size, void* d_ws, size_t ws_size,
                              hipStream_t stream){
  const float* features = (const float*)d_in[0];
  const float* mb       = (const float*)d_in[1];
  const float* noise    = (const float*)d_in[2];
  float* out = (float*)d_out;
  char* ws = (char*)d_ws;

  // fT (32MB exact fp32 transposed features) lives in d_out's noised region; overwritten last.
  float* fT = (float*)d_out;

  size_t off = 0;
  signed char* mq = (signed char*)(ws + off); off += (size_t)MROW * CDIM;   // 16MB
  signed char* fq = (signed char*)(ws + off); off += (size_t)NPOS * CDIM;   // 8MB
  float* m_sq    = (float*)(ws + off); off += (size_t)MROW * 4;
  float* inf_arr = (float*)(ws + off); off += (size_t)NPOS * 4;
  u32* minmax    = (u32*)(ws + off);   off += 256;
  u64* cand      = (u64*)(ws + off);   off += (size_t)NPOS * 128 * 8;       // 8MB

  k_prep<<<4096 + 2048, 256, 0, stream>>>(mb, features, mq, fq, fT, m_sq, minmax);
  k_gemm<<<dim3(2048), 512, 0, stream>>>(fq, mq, m_sq, cand);
  k_finalize<<<2048, 256, 0, stream>>>(cand, fT, mb, m_sq, inf_arr, minmax);
  k_noise<<<dim3(16, 16, 8), 256, 0, stream>>>(features, noise, inf_arr, minmax, out);
}